// Round 16
// baseline (486.525 us; speedup 1.0000x reference)
//
#include <hip/hip_runtime.h>
#include <hip/hip_bf16.h>
#include <math.h>

#define NROWS 16384
#define HID 64
#define KSPLIT 16
#define KCH (NROWS / KSPLIT)  // 1024

typedef __attribute__((ext_vector_type(8))) __bf16 bf16x8;
typedef __attribute__((ext_vector_type(4))) float f32x4;

__device__ inline f32x4 mfma16(bf16x8 a, bf16x8 b, f32x4 c) {
    return __builtin_amdgcn_mfma_f32_16x16x32_bf16(a, b, c, 0, 0, 0);
}

__device__ inline void split8v(const f32x4 v0, const f32x4 v1, bf16x8& h, bf16x8& l) {
    float f[8] = {v0[0], v0[1], v0[2], v0[3], v1[0], v1[1], v1[2], v1[3]};
#pragma unroll
    for (int j = 0; j < 8; ++j) {
        __bf16 hh = (__bf16)f[j];
        h[j] = hh;
        l[j] = (__bf16)(f[j] - (float)hh);
    }
}

// ---------------------------------------------------------------------------
// pack_b: x [16384,64] fp32 row-major  ->  MFMA B-fragment-ordered bf16 hi/lo.
// Packed index: (((kb*4 + t)*64 + lane)*8 + j)
//   holds x[kb*32 + (lane>>4)*8 + j][t*16 + (lane&15)]
// ---------------------------------------------------------------------------
__global__ __launch_bounds__(256) void pack_b(const float* __restrict__ x,
                                              __bf16* __restrict__ hi,
                                              __bf16* __restrict__ lo) {
    __shared__ float tile[32 * 64];
    const int kb = blockIdx.x;  // 0..511, 32 k-rows each
    const f32x4* src = (const f32x4*)(x + (size_t)kb * 32 * 64);
    f32x4* dst = (f32x4*)tile;
    dst[threadIdx.x] = src[threadIdx.x];
    dst[threadIdx.x + 256] = src[threadIdx.x + 256];
    __syncthreads();
    const int t = threadIdx.x >> 6;    // n-tile 0..3
    const int l = threadIdx.x & 63;    // consumer lane
    const int col = (t << 4) + (l & 15);
    const int krow = (l >> 4) * 8;
    bf16x8 h8, l8;
#pragma unroll
    for (int j = 0; j < 8; ++j) {
        float v = tile[(krow + j) * 64 + col];
        __bf16 hh = (__bf16)v;
        h8[j] = hh;
        l8[j] = (__bf16)(v - (float)hh);
    }
    const size_t base = (((size_t)kb * 4 + t) * 64 + l) * 8;
    *(bf16x8*)(hi + base) = h8;
    *(bf16x8*)(lo + base) = l8;
}

// ---------------------------------------------------------------------------
// gemm_partial: partial[ks] = adj[:, ks-chunk] @ x[ks-chunk, :]
// B:A VMEM ratio curve (measured: 2:1 -> 4.4 TB/s, 1:1 -> 5.1, 1:2 -> 5.5):
// final notch G=16 -> 1:4. Wave owns 256 rows (16 x 16-row groups); per 32-k
// step: 32 A-instr + 8 B-instr + 192 MFMA, A issued as 4 quarter-batches
// rotated so >=1 batch is always in flight (peak ~400 VGPR < 450 no-spill).
// Block = 4 waves x 256 rows = 1024 rows; KSPLIT=16 keeps grid = 256 =
// 1 block/CU (BW-bound regime tolerates 1 wave/SIMD -- r15 proof).
// Barrier-free K-loop (r14 lesson). adj loads plain (r3/r4 nt lesson).
// Partial stores nt (no reuse, keep L2 for B).
// ---------------------------------------------------------------------------
__global__ __launch_bounds__(256, 1) void gemm_partial(const float* __restrict__ adj,
                                                       const __bf16* __restrict__ Bhi,
                                                       const __bf16* __restrict__ Blo,
                                                       float* __restrict__ partial) {
    const int lane = threadIdx.x & 63;
    const int wv = threadIdx.x >> 6;   // wave -> 256-row group
    const int rt = blockIdx.x & 15;    // row-tile 0..15 (1024 rows each)
    const int ks = blockIdx.x >> 4;    // k-split 0..15
    const int rbase = rt * 1024 + wv * 256;
    const int rq = lane & 15;          // A row within 16-row group
    const int kq = lane >> 4;          // k-quarter 0..3

    f32x4 acc[16][4];
#pragma unroll
    for (int g = 0; g < 16; ++g)
#pragma unroll
        for (int t = 0; t < 4; ++t) acc[g][t] = f32x4{0.f, 0.f, 0.f, 0.f};

    const float* ap = adj + (size_t)(rbase + rq) * NROWS + ks * KCH + kq * 8;
    const int kk0 = ks * KCH;

#define LOADQ(q, gbase, kk)                                                     \
    {                                                                           \
        _Pragma("unroll") for (int g = 0; g < 4; ++g) {                         \
            const f32x4* a =                                                    \
                (const f32x4*)(ap + (size_t)(((gbase) + g) * 16) * NROWS + kk); \
            q[g][0] = a[0];                                                     \
            q[g][1] = a[1];                                                     \
        }                                                                       \
    }
#define CONSQ(q, gbase)                                                         \
    {                                                                           \
        _Pragma("unroll") for (int g = 0; g < 4; ++g) {                         \
            bf16x8 ah, al;                                                      \
            split8v(q[g][0], q[g][1], ah, al);                                  \
            _Pragma("unroll") for (int t = 0; t < 4; ++t) {                     \
                acc[(gbase) + g][t] = mfma16(ah, bh[t], acc[(gbase) + g][t]);   \
                acc[(gbase) + g][t] = mfma16(ah, bl[t], acc[(gbase) + g][t]);   \
                acc[(gbase) + g][t] = mfma16(al, bh[t], acc[(gbase) + g][t]);   \
            }                                                                   \
        }                                                                       \
    }

    for (int kk = 0; kk < KCH; kk += 32) {
        f32x4 q0[4][2], q1[4][2], q2[4][2], q3[4][2];
        LOADQ(q0, 0, kk);
        // B fragments (L2/L1-resident packed bf16), 8 x 16B, wave-shared
        const size_t bb = ((size_t)((kk0 + kk) >> 5) * 4) * 512 + (size_t)lane * 8;
        bf16x8 bh[4], bl[4];
#pragma unroll
        for (int t = 0; t < 4; ++t) {
            bh[t] = *(const bf16x8*)(Bhi + bb + (size_t)t * 512);
            bl[t] = *(const bf16x8*)(Blo + bb + (size_t)t * 512);
        }
        LOADQ(q1, 4, kk);
        CONSQ(q0, 0);        // waits q0+B; q1 flying
        LOADQ(q2, 8, kk);
        CONSQ(q1, 4);        // q2 flying
        LOADQ(q3, 12, kk);
        CONSQ(q2, 8);        // q3 flying
        CONSQ(q3, 12);
    }

    // C/D layout: col = lane&15, row = (lane>>4)*4 + reg   [m89-verified]
    float* pp = partial + (size_t)ks * (NROWS * HID) + (size_t)rbase * HID;
#pragma unroll
    for (int g = 0; g < 16; ++g)
#pragma unroll
        for (int t = 0; t < 4; ++t)
#pragma unroll
            for (int r = 0; r < 4; ++r)
                __builtin_nontemporal_store(acc[g][t][r],
                    pp + (g * 16 + kq * 4 + r) * HID + t * 16 + rq);
}

// ---------------------------------------------------------------------------
// reduce_dense(+optional fused pack): agg_r = sum_ks partial[ks][r];
// v = tanh([agg_r|x_r] @ W); writes xout, and when hi!=null also emits the
// bf16 hi/lo packed-B form of v for the next hop's gemm.
// ---------------------------------------------------------------------------
__global__ __launch_bounds__(256) void reduce_dense(const float* __restrict__ partial,
                                                    const float* __restrict__ xin,
                                                    const float* __restrict__ W,
                                                    float* __restrict__ xout,
                                                    __bf16* __restrict__ hi,
                                                    __bf16* __restrict__ lo) {
    __shared__ float wsm[128 * 64];  // 32 KB
    __shared__ float xt[32][64];     // 8 KB: this block's 32 output rows
    const f32x4* wsrc = (const f32x4*)W;
    f32x4* wdst = (f32x4*)wsm;
#pragma unroll
    for (int i = 0; i < 8; ++i) wdst[threadIdx.x + 256 * i] = wsrc[threadIdx.x + 256 * i];
    __syncthreads();

    const int lane = threadIdx.x & 63;
    const int wv = threadIdx.x >> 6;
    const int r0 = blockIdx.x * 32 + wv * 8;
#pragma unroll 2
    for (int i = 0; i < 8; ++i) {
        const int r = r0 + i;
        float av = 0.f;
#pragma unroll
        for (int ks = 0; ks < KSPLIT; ++ks)
            av += partial[(size_t)ks * (NROWS * HID) + (size_t)r * HID + lane];
        const float xv = xin[(size_t)r * HID + lane];
        float z = 0.f;
#pragma unroll
        for (int j = 0; j < 64; ++j) z += __shfl(av, j) * wsm[j * 64 + lane];
#pragma unroll
        for (int j = 0; j < 64; ++j) z += __shfl(xv, j) * wsm[(64 + j) * 64 + lane];
        const float v = tanhf(z);
        xout[(size_t)r * HID + lane] = v;
        xt[wv * 8 + i][lane] = v;
    }

    if (hi != nullptr) {
        __syncthreads();
        const int t = threadIdx.x >> 6;
        const int l = threadIdx.x & 63;
        const int col = (t << 4) + (l & 15);
        const int krow = (l >> 4) * 8;
        bf16x8 h8, l8;
#pragma unroll
        for (int j = 0; j < 8; ++j) {
            float v = xt[krow + j][col];
            __bf16 hh = (__bf16)v;
            h8[j] = hh;
            l8[j] = (__bf16)(v - (float)hh);
        }
        const size_t base = (((size_t)blockIdx.x * 4 + t) * 64 + l) * 8;
        *(bf16x8*)(hi + base) = h8;
        *(bf16x8*)(lo + base) = l8;
    }
}

extern "C" void kernel_launch(void* const* d_in, const int* in_sizes, int n_in,
                              void* d_out, int out_size, void* d_ws, size_t ws_size,
                              hipStream_t stream) {
    const float* x0 = (const float*)d_in[0];   // user_embs [16384,64]
    const float* adj = (const float*)d_in[1];  // adj [16384,16384]
    const float* W = (const float*)d_in[2];    // W [2,128,64]
    float* out = (float*)d_out;

    char* ws = (char*)d_ws;
    __bf16* Bhi = (__bf16*)(ws);                       // 2 MB
    __bf16* Blo = (__bf16*)(ws + (2u << 20));          // 2 MB
    float* partial = (float*)(ws + (4u << 20));        // 64 MB (16 x 4 MB)
    float* x1 = (float*)(ws + (68u << 20));            // 4 MB

    // hop 0
    pack_b<<<512, 256, 0, stream>>>(x0, Bhi, Blo);
    gemm_partial<<<KSPLIT * 16, 256, 0, stream>>>(adj, Bhi, Blo, partial);
    reduce_dense<<<512, 256, 0, stream>>>(partial, x0, W, x1, Bhi, Blo);  // fused pack
    // hop 1
    gemm_partial<<<KSPLIT * 16, 256, 0, stream>>>(adj, Bhi, Blo, partial);
    reduce_dense<<<512, 256, 0, stream>>>(partial, x1, W + 128 * 64, out, nullptr, nullptr);
}

// Round 17
// 453.960 us; speedup vs baseline: 1.0717x; 1.0717x over previous
//
#include <hip/hip_runtime.h>
#include <hip/hip_bf16.h>
#include <math.h>

#define NROWS 16384
#define HID 64
#define KSPLIT 8
#define KCH (NROWS / KSPLIT)  // 2048

typedef __attribute__((ext_vector_type(8))) __bf16 bf16x8;
typedef __attribute__((ext_vector_type(4))) float f32x4;

__device__ inline f32x4 mfma16(bf16x8 a, bf16x8 b, f32x4 c) {
    return __builtin_amdgcn_mfma_f32_16x16x32_bf16(a, b, c, 0, 0, 0);
}

__device__ inline void split8v(const f32x4 v0, const f32x4 v1, bf16x8& h, bf16x8& l) {
    float f[8] = {v0[0], v0[1], v0[2], v0[3], v1[0], v1[1], v1[2], v1[3]};
#pragma unroll
    for (int j = 0; j < 8; ++j) {
        __bf16 hh = (__bf16)f[j];
        h[j] = hh;
        l[j] = (__bf16)(f[j] - (float)hh);
    }
}

// ---------------------------------------------------------------------------
// pack_b: x [16384,64] fp32 row-major  ->  MFMA B-fragment-ordered bf16 hi/lo.
// Packed index: (((kb*4 + t)*64 + lane)*8 + j)
//   holds x[kb*32 + (lane>>4)*8 + j][t*16 + (lane&15)]
// ---------------------------------------------------------------------------
__global__ __launch_bounds__(256) void pack_b(const float* __restrict__ x,
                                              __bf16* __restrict__ hi,
                                              __bf16* __restrict__ lo) {
    __shared__ float tile[32 * 64];
    const int kb = blockIdx.x;  // 0..511, 32 k-rows each
    const f32x4* src = (const f32x4*)(x + (size_t)kb * 32 * 64);
    f32x4* dst = (f32x4*)tile;
    dst[threadIdx.x] = src[threadIdx.x];
    dst[threadIdx.x + 256] = src[threadIdx.x + 256];
    __syncthreads();
    const int t = threadIdx.x >> 6;    // n-tile 0..3
    const int l = threadIdx.x & 63;    // consumer lane
    const int col = (t << 4) + (l & 15);
    const int krow = (l >> 4) * 8;
    bf16x8 h8, l8;
#pragma unroll
    for (int j = 0; j < 8; ++j) {
        float v = tile[(krow + j) * 64 + col];
        __bf16 hh = (__bf16)v;
        h8[j] = hh;
        l8[j] = (__bf16)(v - (float)hh);
    }
    const size_t base = (((size_t)kb * 4 + t) * 64 + l) * 8;
    *(bf16x8*)(hi + base) = h8;
    *(bf16x8*)(lo + base) = l8;
}

// ---------------------------------------------------------------------------
// gemm_partial: partial[ks] = adj[:, ks-chunk] @ x[ks-chunk, :]
// CHAMPION (r15, 453.7us): barrier-free, B:A VMEM = 1:2 (measured ratio
// curve 2:1->4.4, 1:1->5.1, 1:2->5.5 TB/s; G=16/1:4 regressed via VGPR
// pressure + doubled partial traffic, r16). G=8: wave owns 128 rows
// (8 x 16-row groups); per 32-k step: 16 A-instr + 8 B-instr + 96 MFMA.
// A loaded in two 4-group half-batches so batch 2 flies under batch 1's
// MFMAs. Block = 4 waves x 128 rows = 512 rows; grid = 32 rt x 8 ks = 256
// = 1 block/CU (BW-bound regime tolerates 1 wave/SIMD; r6/r7/r15 evidence).
// launch_bounds(256,1): ~235 VGPR, no spill. No barriers in the K-loop
// (r14 lesson). adj loads plain (r3/r4 nt lesson). Partial stores nt.
// ---------------------------------------------------------------------------
__global__ __launch_bounds__(256, 1) void gemm_partial(const float* __restrict__ adj,
                                                       const __bf16* __restrict__ Bhi,
                                                       const __bf16* __restrict__ Blo,
                                                       float* __restrict__ partial) {
    const int lane = threadIdx.x & 63;
    const int wv = threadIdx.x >> 6;   // wave -> 128-row group
    const int rt = blockIdx.x & 31;    // row-tile 0..31 (512 rows each)
    const int ks = blockIdx.x >> 5;    // k-split 0..7
    const int rbase = rt * 512 + wv * 128;
    const int rq = lane & 15;          // A row within 16-row group
    const int kq = lane >> 4;          // k-quarter 0..3

    f32x4 acc[8][4];
#pragma unroll
    for (int g = 0; g < 8; ++g)
#pragma unroll
        for (int t = 0; t < 4; ++t) acc[g][t] = f32x4{0.f, 0.f, 0.f, 0.f};

    const float* ap = adj + (size_t)(rbase + rq) * NROWS + ks * KCH + kq * 8;
    const int kk0 = ks * KCH;

    for (int kk = 0; kk < KCH; kk += 32) {
        // A half-batch 1: groups 0-3 (8 instrs, oldest in queue)
        f32x4 av0[4][2];
#pragma unroll
        for (int g = 0; g < 4; ++g) {
            const f32x4* a = (const f32x4*)(ap + (size_t)(g * 16) * NROWS + kk);
            av0[g][0] = a[0];
            av0[g][1] = a[1];
        }
        // B fragments (L2/L1-resident packed bf16), 8 x 16B, wave-shared
        const size_t bb = ((size_t)((kk0 + kk) >> 5) * 4) * 512 + (size_t)lane * 8;
        bf16x8 bh[4], bl[4];
#pragma unroll
        for (int t = 0; t < 4; ++t) {
            bh[t] = *(const bf16x8*)(Bhi + bb + (size_t)t * 512);
            bl[t] = *(const bf16x8*)(Blo + bb + (size_t)t * 512);
        }
        // A half-batch 2: groups 4-7 (youngest; in flight during MFMAs below)
        f32x4 av1[4][2];
#pragma unroll
        for (int g = 0; g < 4; ++g) {
            const f32x4* a = (const f32x4*)(ap + (size_t)((g + 4) * 16) * NROWS + kk);
            av1[g][0] = a[0];
            av1[g][1] = a[1];
        }
        // consume groups 0-3 (only waits on av0+B; av1 still flying)
#pragma unroll
        for (int g = 0; g < 4; ++g) {
            bf16x8 ah, al;
            split8v(av0[g][0], av0[g][1], ah, al);
#pragma unroll
            for (int t = 0; t < 4; ++t) {
                acc[g][t] = mfma16(ah, bh[t], acc[g][t]);
                acc[g][t] = mfma16(ah, bl[t], acc[g][t]);
                acc[g][t] = mfma16(al, bh[t], acc[g][t]);
            }
        }
        // consume groups 4-7
#pragma unroll
        for (int g = 0; g < 4; ++g) {
            bf16x8 ah, al;
            split8v(av1[g][0], av1[g][1], ah, al);
#pragma unroll
            for (int t = 0; t < 4; ++t) {
                acc[g + 4][t] = mfma16(ah, bh[t], acc[g + 4][t]);
                acc[g + 4][t] = mfma16(ah, bl[t], acc[g + 4][t]);
                acc[g + 4][t] = mfma16(al, bh[t], acc[g + 4][t]);
            }
        }
    }

    // C/D layout: col = lane&15, row = (lane>>4)*4 + reg   [m89-verified]
    float* pp = partial + (size_t)ks * (NROWS * HID) + (size_t)rbase * HID;
#pragma unroll
    for (int g = 0; g < 8; ++g)
#pragma unroll
        for (int t = 0; t < 4; ++t)
#pragma unroll
            for (int r = 0; r < 4; ++r)
                __builtin_nontemporal_store(acc[g][t][r],
                    pp + (g * 16 + kq * 4 + r) * HID + t * 16 + rq);
}

// ---------------------------------------------------------------------------
// reduce_dense(+optional fused pack): agg_r = sum_ks partial[ks][r];
// v = tanh([agg_r|x_r] @ W); writes xout, and when hi!=null also emits the
// bf16 hi/lo packed-B form of v for the next hop's gemm (saves the pack_b
// launch + x1 re-read). Block handles rows [blockIdx*32, +32) = pack kb.
// ---------------------------------------------------------------------------
__global__ __launch_bounds__(256) void reduce_dense(const float* __restrict__ partial,
                                                    const float* __restrict__ xin,
                                                    const float* __restrict__ W,
                                                    float* __restrict__ xout,
                                                    __bf16* __restrict__ hi,
                                                    __bf16* __restrict__ lo) {
    __shared__ float wsm[128 * 64];  // 32 KB
    __shared__ float xt[32][64];     // 8 KB: this block's 32 output rows
    const f32x4* wsrc = (const f32x4*)W;
    f32x4* wdst = (f32x4*)wsm;
#pragma unroll
    for (int i = 0; i < 8; ++i) wdst[threadIdx.x + 256 * i] = wsrc[threadIdx.x + 256 * i];
    __syncthreads();

    const int lane = threadIdx.x & 63;
    const int wv = threadIdx.x >> 6;
    const int r0 = blockIdx.x * 32 + wv * 8;
#pragma unroll 2
    for (int i = 0; i < 8; ++i) {
        const int r = r0 + i;
        float av = 0.f;
#pragma unroll
        for (int ks = 0; ks < KSPLIT; ++ks)
            av += partial[(size_t)ks * (NROWS * HID) + (size_t)r * HID + lane];
        const float xv = xin[(size_t)r * HID + lane];
        float z = 0.f;
#pragma unroll
        for (int j = 0; j < 64; ++j) z += __shfl(av, j) * wsm[j * 64 + lane];
#pragma unroll
        for (int j = 0; j < 64; ++j) z += __shfl(xv, j) * wsm[(64 + j) * 64 + lane];
        const float v = tanhf(z);
        xout[(size_t)r * HID + lane] = v;
        xt[wv * 8 + i][lane] = v;
    }

    if (hi != nullptr) {
        __syncthreads();
        const int t = threadIdx.x >> 6;
        const int l = threadIdx.x & 63;
        const int col = (t << 4) + (l & 15);
        const int krow = (l >> 4) * 8;
        bf16x8 h8, l8;
#pragma unroll
        for (int j = 0; j < 8; ++j) {
            float v = xt[krow + j][col];
            __bf16 hh = (__bf16)v;
            h8[j] = hh;
            l8[j] = (__bf16)(v - (float)hh);
        }
        const size_t base = (((size_t)blockIdx.x * 4 + t) * 64 + l) * 8;
        *(bf16x8*)(hi + base) = h8;
        *(bf16x8*)(lo + base) = l8;
    }
}

extern "C" void kernel_launch(void* const* d_in, const int* in_sizes, int n_in,
                              void* d_out, int out_size, void* d_ws, size_t ws_size,
                              hipStream_t stream) {
    const float* x0 = (const float*)d_in[0];   // user_embs [16384,64]
    const float* adj = (const float*)d_in[1];  // adj [16384,16384]
    const float* W = (const float*)d_in[2];    // W [2,128,64]
    float* out = (float*)d_out;

    char* ws = (char*)d_ws;
    __bf16* Bhi = (__bf16*)(ws);                       // 2 MB
    __bf16* Blo = (__bf16*)(ws + (2u << 20));          // 2 MB
    float* partial = (float*)(ws + (4u << 20));        // 32 MB (8 x 4 MB)
    float* x1 = (float*)(ws + (36u << 20));            // 4 MB

    // hop 0
    pack_b<<<512, 256, 0, stream>>>(x0, Bhi, Blo);
    gemm_partial<<<KSPLIT * 32, 256, 0, stream>>>(adj, Bhi, Blo, partial);
    reduce_dense<<<512, 256, 0, stream>>>(partial, x0, W, x1, Bhi, Blo);  // fused pack
    // hop 1
    gemm_partial<<<KSPLIT * 32, 256, 0, stream>>>(adj, Bhi, Blo, partial);
    reduce_dense<<<512, 256, 0, stream>>>(partial, x1, W + 128 * 64, out, nullptr, nullptr);
}